// Round 14
// baseline (48.372 us; speedup 1.0000x reference)
//
#include <hip/hip_runtime.h>
#include <cstdint>

// WealthRNN v16: wave0 = compute + DIRECT coalesced dword stores (no output
// LDS round-trip, no counted vmcnt in wave0); wave1 = PURE DMA loader (full
// 63-op outstanding budget on loads). Batch = 16 groups (64 steps) per
// barrier -> 17 barriers. Ring 64 slots x 2KiB = 128KiB LDS.
//
// Loader audit (DMA ops only, in-order vmcnt):
//   prologue: 32 groups (64 ops), WAITV(28) -> groups 0..17 done, barrier#0
//   k=0..12: dma batch k+2 (16 gr); WAITV(28) -> thru group 16k+33; bar#k+1
//   k=13: dma batch 15 (15 gr); WAITV(26) -> thru 241; bar#14
//   k=14: WAITV(0) (all 255 groups); bar#15;  then bar#16
// wave0 audit: DS stream = reads only; phase g issues RDG(g+2), waits
//   LGKMN(8) (= 2 younger RDGs) -> group g's reads (2 phases old) retired.
//   Slot safety: interval k writes slots {16k+32..47}&63, batch k reads
//   {16k..16k+17}&63 -> disjoint; overwritten group g-64 consumed 2 batches
//   earlier. Stores: 4/group, never >~20 outstanding; WAITV(0) at end.

#define S_LEN 1024
#define B_LEN 16384
#define GSTEP ((size_t)4 * B_LEN)

typedef uint32_t u32x4 __attribute__((ext_vector_type(4)));
typedef float    f32x2 __attribute__((ext_vector_type(2)));

__device__ __forceinline__ u32x4 make_srsrc(const void* p) {
    u32x4 r;
    uint64_t a = (uint64_t)p;
    r.x = (uint32_t)a;
    r.y = (uint32_t)(a >> 32);
    r.z = 0xFFFFFFFFu;
    r.w = 0x00020000u;
    return r;
}

#define SBAR0 __builtin_amdgcn_sched_barrier(0)
#define WAITV(N) do { asm volatile("s_waitcnt vmcnt(%0)" :: "n"(N)); SBAR0; } while (0)
#define LGKMN(N) do { asm volatile("s_waitcnt lgkmcnt(%0)" :: "n"(N)); SBAR0; } while (0)

__device__ __forceinline__ void dma16(const float* g, float* l) {
    __builtin_amdgcn_global_load_lds(
        (const __attribute__((address_space(1))) void*)g,
        (__attribute__((address_space(3))) void*)l, 16, 0, 0);
}

// exact step (tail only)
__device__ __forceinline__ float step_fn(float h, float x, float r,
                                         float win, float wh,
                                         float c1, float c2, float c3,
                                         float wf1, float wf2) {
    float inv   = __builtin_amdgcn_rcpf(fmaf(h, r, 1.0f));
    float h_adj = fmaf(h, r, h) * inv;
    float ingate = fmaf(wh, h_adj, fmaf(x, win, c1));
    float t  = fmaxf(ingate, 0.0f);
    float g2 = fmaf(wf1, t, c2);
    float t2 = fmaxf(g2, 0.0f);
    return fmaf(wf2, t2, c3);
}

// verified re-rooted chain (R12/R13: absmax <= 0.008 vs threshold 0.077)
struct Consts { float winwf1, whwf1, c1wf1c2, c2p, wf2, c3; };

template<bool POS>
__device__ __forceinline__ void step_fast(float& st, float& hv,
                                          float x, float r, const Consts& C) {
    float A1 = C.wf2 * r;
    float B1 = C.c3 * r;
    float w  = fmaf(C.whwf1, r, C.whwf1);
    float A2 = C.wf2 * w;
    float B2 = C.c3 * w;
    float KK = fmaf(x, C.winwf1, C.c1wf1c2);
    float u  = fmaf(A1, st, B1);
    float M  = fmaf(A2, st, B2);
    float q  = fmaf(u, u, 1.0f);
    float om = 1.0f - u;
    float p  = om * q;
    float Aa = fmaf(M, p, KK);
    if (POS) st = fmaxf(Aa, C.c2p);
    else     st = fminf(fmaxf(Aa, 0.0f), C.c2p);
    hv = fmaf(C.wf2, st, C.c3);
}

template<bool POS>
__device__ __forceinline__ void step_first(float& st, float& hv,
                                           float x, float r, float h0,
                                           const Consts& C) {
    float w  = fmaf(C.whwf1, r, C.whwf1);
    float KK = fmaf(x, C.winwf1, C.c1wf1c2);
    float u  = h0 * r;
    float M  = w * h0;
    float q  = fmaf(u, u, 1.0f);
    float om = 1.0f - u;
    float p  = om * q;
    float Aa = fmaf(M, p, KK);
    if (POS) st = fmaxf(Aa, C.c2p);
    else     st = fminf(fmaxf(Aa, 0.0f), C.c2p);
    hv = fmaf(C.wf2, st, C.c3);
}

struct Bank { f32x2 x01, x23, r01, r23; };

// ds_read2 offsets are in DWORDS: offset1:64 = +256B (row stride)
#define RDGA(AX_, BK) do { \
    uint32_t ar_ = (AX_) + 1024u; \
    asm volatile("ds_read2_b32 %0, %1 offset0:0 offset1:64"    : "=v"((BK).x01) : "v"(AX_)); \
    asm volatile("ds_read2_b32 %0, %1 offset0:128 offset1:192" : "=v"((BK).x23) : "v"(AX_)); \
    asm volatile("ds_read2_b32 %0, %1 offset0:0 offset1:64"    : "=v"((BK).r01) : "v"(ar_)); \
    asm volatile("ds_read2_b32 %0, %1 offset0:128 offset1:192" : "=v"((BK).r23) : "v"(ar_)); \
} while (0)

#define BSTROW(HV_, ROWC_) do { \
    uint32_t so_ = sob + (uint32_t)((ROWC_) << 16); \
    asm volatile("buffer_store_dword %0, %1, %2, %3 offen" \
                 :: "v"(HV_), "v"(voff), "s"(ro), "s"(so_)); \
} while (0)

// one phase: read group g0+p+2 (clamped) -> BKR; wait; 4 pure-C++ steps from
// BKC; 4 direct stores (rows 64bt+4p+1..+4).
#define PH(p_, BKR, BKC) do { \
    int gr_ = g0 + (p_) + 2; if (gr_ > 254) gr_ = 254; \
    { uint32_t ra_ = rbase + (uint32_t)((gr_ & 63) * 2048); RDGA(ra_, BKR); } \
    LGKMN(8); \
    step_fast<POS>(st, hv0, (BKC).x01.x, (BKC).r01.x, C); \
    step_fast<POS>(st, hv1, (BKC).x01.y, (BKC).r01.y, C); \
    step_fast<POS>(st, hv2, (BKC).x23.x, (BKC).r23.x, C); \
    step_fast<POS>(st, hv3, (BKC).x23.y, (BKC).r23.y, C); \
    BSTROW(hv0, 4 * (p_) + 1); BSTROW(hv1, 4 * (p_) + 2); \
    BSTROW(hv2, 4 * (p_) + 3); BSTROW(hv3, 4 * (p_) + 4); \
} while (0)

template<bool POS>
__device__ __forceinline__ void wave0_impl(
    const float* inputs, const float* returns,
    float pi_bar, float win, float wh, float bh, float wf1, float wf2,
    float* out, int b0, int lane, float* ringp)
{
    const int b = b0 + lane;
    const float c1 = bh - pi_bar;
    const float c2 = 2.0f * bh;
    const float c3 = pi_bar + bh;
    Consts C;
    C.winwf1  = win * wf1;
    C.whwf1   = wh * wf1;
    C.c1wf1c2 = fmaf(c1, wf1, c2);
    C.c2p     = fmaxf(c2, 0.0f);
    C.wf2     = wf2;
    C.c3      = c3;

    const float h0v = inputs[b];
    out[b] = h0v;                               // row 0 (pre-region)

    u32x4 ro = make_srsrc(out);
    const uint32_t voff = (uint32_t)(b * 4);
    const uint32_t rbase = (uint32_t)(uintptr_t)ringp + (uint32_t)lane * 4u;

    asm volatile("" ::: "memory");
    __builtin_amdgcn_s_barrier();               // #0 (groups 0..17 ready)

    Bank B0, B1, B2, B3;
    float st = 0.0f, hv0, hv1, hv2, hv3;

    { uint32_t ra_ = rbase;          RDGA(ra_, B0); }
    { uint32_t ra_ = rbase + 2048u;  RDGA(ra_, B1); }
    LGKMN(0);

    // batches 0..14 (16 groups each): phase p consumes bank p%4, reads (p+2)%4
    for (int bt = 0; bt < 15; ++bt) {
        const int g0 = 16 * bt;
        const uint32_t sob = (uint32_t)(64 * bt) << 16;
        if (bt == 0) {
            // phase 0 seeded from h0
            { uint32_t ra_ = rbase + (uint32_t)(((g0 + 2) & 63) * 2048); RDGA(ra_, B2); }
            LGKMN(8);
            step_first<POS>(st, hv0, B0.x01.x, B0.r01.x, h0v, C);
            step_fast<POS>(st, hv1, B0.x01.y, B0.r01.y, C);
            step_fast<POS>(st, hv2, B0.x23.x, B0.r23.x, C);
            step_fast<POS>(st, hv3, B0.x23.y, B0.r23.y, C);
            BSTROW(hv0, 1); BSTROW(hv1, 2); BSTROW(hv2, 3); BSTROW(hv3, 4);
        } else {
            PH(0, B2, B0);
        }
        PH(1,  B3, B1); PH(2,  B0, B2); PH(3,  B1, B3);
        PH(4,  B2, B0); PH(5,  B3, B1); PH(6,  B0, B2); PH(7,  B1, B3);
        PH(8,  B2, B0); PH(9,  B3, B1); PH(10, B0, B2); PH(11, B1, B3);
        PH(12, B2, B0); PH(13, B3, B1); PH(14, B0, B2); PH(15, B1, B3);
        __builtin_amdgcn_s_barrier();           // #bt+1
    }
    // batch 15: groups 240..254 (15 phases, rows 961..1020)
    {
        const int g0 = 240;
        const uint32_t sob = (uint32_t)(960) << 16;
        PH(0,  B2, B0); PH(1,  B3, B1); PH(2,  B0, B2); PH(3,  B1, B3);
        PH(4,  B2, B0); PH(5,  B3, B1); PH(6,  B0, B2); PH(7,  B1, B3);
        PH(8,  B2, B0); PH(9,  B3, B1); PH(10, B0, B2); PH(11, B1, B3);
        PH(12, B2, B0); PH(13, B3, B1); PH(14, B0, B2);
        __builtin_amdgcn_s_barrier();           // #16
    }
    LGKMN(0);
    asm volatile("" ::: "memory");

    // tail steps 1021..1023 + hT (exact)
    float h = hv3;                               // h_1020
#pragma unroll
    for (int s = 1021; s < S_LEN; ++s) {
        const float x = inputs[(size_t)s * B_LEN + b];
        const float r = returns[(size_t)(s - 1) * B_LEN + b];
        h = step_fn(h, x, r, win, wh, c1, c2, c3, wf1, wf2);
        out[(size_t)s * B_LEN + b] = h;
    }
    out[(size_t)S_LEN * B_LEN + b] = h;

    WAITV(0);                                    // drain asm stores pre-endpgm
}

#define DMA_GROUP() do { \
    float* lb_ = &ringf[(size_t)(dmag & 63) * 512]; \
    dma16(gxw, lb_); dma16(grw, lb_ + 256); \
    gxw += GSTEP; grw += GSTEP; ++dmag; \
} while (0)

__global__ __launch_bounds__(128) void wealth_rnn_kernel(
    const float* __restrict__ inputs,    // [S, B]
    const float* __restrict__ returns,   // [S-1, B]
    const float* __restrict__ target,
    const float* __restrict__ w_in_p,
    const float* __restrict__ w_h_p,
    const float* __restrict__ b_h_p,
    const float* __restrict__ w_fc1_p,
    const float* __restrict__ w_fc2_p,
    float* __restrict__ out)             // [S*B] then [B] hT
{
    __shared__ float ringf[64 * 512];    // 128 KiB input ring (64 groups)

    const int tid  = threadIdx.x;
    const int lane = tid & 63;
    const int wid  = tid >> 6;
    const int b0   = blockIdx.x * 64;

    if (wid == 0) {
        const float pi_bar = target[0];
        const float win = w_in_p[0];
        const float wh  = w_h_p[0];
        const float bh  = b_h_p[0];
        const float wf1 = w_fc1_p[0];
        const float wf2 = w_fc2_p[0];
        if (wf1 >= 0.0f)
            wave0_impl<true >(inputs, returns, pi_bar, win, wh, bh, wf1, wf2,
                              out, b0, lane, &ringf[0]);
        else
            wave0_impl<false>(inputs, returns, pi_bar, win, wh, bh, wf1, wf2,
                              out, b0, lane, &ringf[0]);
    } else {
        // ======================== pure DMA loader ===========================
        const int j = lane;
        const int lr = j >> 4;
        const int lc = (j & 15) * 4;
        const float* gxw = inputs  + (size_t)(1 + lr) * B_LEN + b0 + lc;
        const float* grw = returns + (size_t)lr       * B_LEN + b0 + lc;
        int dmag = 0;

        // prologue: groups 0..31 (64 ops); groups 0..17 must land
        for (int gi = 0; gi < 32; ++gi) { DMA_GROUP(); }
        WAITV(28);
        __builtin_amdgcn_s_barrier();     // #0

        // k = 0..12: dma batch k+2 (16 groups); thru group 16k+33 by next bar
        for (int k = 0; k < 13; ++k) {
            for (int gi = 0; gi < 16; ++gi) { DMA_GROUP(); }
            WAITV(28);
            __builtin_amdgcn_s_barrier(); // #k+1
        }
        // k=13: batch 15 (15 groups, 240..254); thru 241 by bar#14
        for (int gi = 0; gi < 15; ++gi) { DMA_GROUP(); }
        WAITV(26);
        __builtin_amdgcn_s_barrier();     // #14
        // k=14: everything (thru 254) by bar#15
        WAITV(0);
        __builtin_amdgcn_s_barrier();     // #15
        __builtin_amdgcn_s_barrier();     // #16
    }
}

extern "C" void kernel_launch(void* const* d_in, const int* in_sizes, int n_in,
                              void* d_out, int out_size, void* d_ws, size_t ws_size,
                              hipStream_t stream) {
    const float* inputs  = (const float*)d_in[0];
    const float* returns = (const float*)d_in[1];
    const float* target  = (const float*)d_in[2];
    const float* w_in    = (const float*)d_in[3];
    const float* w_h     = (const float*)d_in[4];
    const float* b_h     = (const float*)d_in[5];
    const float* w_fc1   = (const float*)d_in[6];
    const float* w_fc2   = (const float*)d_in[7];
    float* out = (float*)d_out;

    dim3 grid(B_LEN / 64);
    dim3 block(128);
    hipLaunchKernelGGL(wealth_rnn_kernel, grid, block, 0, stream,
                       inputs, returns, target, w_in, w_h, b_h, w_fc1, w_fc2, out);
}

// Round 16
// 41.057 us; speedup vs baseline: 1.1782x; 1.1782x over previous
//
#include <hip/hip_runtime.h>
#include <cstdint>

// WealthRNN v18 = v17 with one compile fix: SD_ST's store offset moves from
// a runtime soffset ("s" constraint -> compiler put it in a VGPR, invalid)
// into the 32-bit voffset VGPR (vo_ = vo + row*65536; soffset literal 0).
//  w0: compute. Per step: 2 ds_read2st64 (Mobius coeffs) + fmaf,fmaf,rcp,
//      mul,clamp + 0.5 ds_write2st64 (st out). ~8 instr/step.
//  w1/w2: producers: alpha',beta',gamma,delta from (x,r), 1 batch ahead;
//      also store outputs of batch k-1 (hv = wf2*st+c3). Even/odd groups.
//  w3: pure DMA loader (x/r ring, 3-batch rotation, lead 3).
// Audits (from R15, unchanged): w0 lgkm q0:8,q1..6:10,q7:2,end:0; producer
// lgkm 4,12,12,8,end0; loader vmcnt WAITV(16)/(14)/(0); producer WAITV(4)
// before reg-set reuse; barriers P1,#0..#32 = 34 on every wave.

#define S_LEN 1024
#define B_LEN 16384
#define GSTEP ((size_t)4 * B_LEN)

typedef uint32_t u32x4 __attribute__((ext_vector_type(4)));
typedef float    f32x4 __attribute__((ext_vector_type(4)));
typedef float    f32x2 __attribute__((ext_vector_type(2)));

__device__ __forceinline__ u32x4 make_srsrc(const void* p) {
    u32x4 r;
    uint64_t a = (uint64_t)p;
    r.x = (uint32_t)a;
    r.y = (uint32_t)(a >> 32);
    r.z = 0xFFFFFFFFu;
    r.w = 0x00020000u;
    return r;
}

#define SBAR0 __builtin_amdgcn_sched_barrier(0)
#define WAITV(N) do { asm volatile("s_waitcnt vmcnt(%0)" :: "n"(N)); SBAR0; } while (0)
#define LGKMN(N) do { asm volatile("s_waitcnt lgkmcnt(%0)" :: "n"(N)); SBAR0; } while (0)
#define BAR __builtin_amdgcn_s_barrier()

__device__ __forceinline__ void dma16(const float* g, float* l) {
    __builtin_amdgcn_global_load_lds(
        (const __attribute__((address_space(1))) void*)g,
        (__attribute__((address_space(3))) void*)l, 16, 0, 0);
}

// exact step (w0 tail only)
__device__ __forceinline__ float step_fn(float h, float x, float r,
                                         float win, float wh,
                                         float c1, float c2, float c3,
                                         float wf1, float wf2) {
    float inv   = __builtin_amdgcn_rcpf(fmaf(h, r, 1.0f));
    float h_adj = fmaf(h, r, h) * inv;
    float ingate = fmaf(wh, h_adj, fmaf(x, win, c1));
    float t  = fmaxf(ingate, 0.0f);
    float g2 = fmaf(wf1, t, c2);
    float t2 = fmaxf(g2, 0.0f);
    return fmaf(wf2, t2, c3);
}

// Mobius chain step: st' = clamp((a*st+b)/(g*st+d))
template<bool POS>
__device__ __forceinline__ void mstep(float& st, f32x2 ab, f32x2 gd, float c2p) {
    float n = fmaf(ab.x, st, ab.y);
    float d = fmaf(gd.x, st, gd.y);
    float i = __builtin_amdgcn_rcpf(d);
    float A = n * i;
    if (POS) st = fmaxf(A, c2p);
    else     st = fminf(fmaxf(A, 0.0f), c2p);
}

struct CSet { f32x2 ab0, gd0, ab1, gd1, ab2, gd2, ab3, gd3; };
struct Bank { f32x2 x01, x23, r01, r23; };

// coeff layout per group (4KB): step s: a@4s, b@4s+1, g@4s+2, d@4s+3 (st64 units)
#define RDC(ADDR_, S_) do { uint32_t a_ = (ADDR_); \
    asm volatile("ds_read2st64_b32 %0, %1 offset0:0 offset1:1"   : "=v"((S_).ab0) : "v"(a_)); \
    asm volatile("ds_read2st64_b32 %0, %1 offset0:2 offset1:3"   : "=v"((S_).gd0) : "v"(a_)); \
    asm volatile("ds_read2st64_b32 %0, %1 offset0:4 offset1:5"   : "=v"((S_).ab1) : "v"(a_)); \
    asm volatile("ds_read2st64_b32 %0, %1 offset0:6 offset1:7"   : "=v"((S_).gd1) : "v"(a_)); \
    asm volatile("ds_read2st64_b32 %0, %1 offset0:8 offset1:9"   : "=v"((S_).ab2) : "v"(a_)); \
    asm volatile("ds_read2st64_b32 %0, %1 offset0:10 offset1:11" : "=v"((S_).gd2) : "v"(a_)); \
    asm volatile("ds_read2st64_b32 %0, %1 offset0:12 offset1:13" : "=v"((S_).ab3) : "v"(a_)); \
    asm volatile("ds_read2st64_b32 %0, %1 offset0:14 offset1:15" : "=v"((S_).gd3) : "v"(a_)); \
} while (0)

// w0 phase: wait, 4 chain steps, write st tile, optional prefetch q+2
#define W0_PH(Q_, SET_, LGN_, DORD_) do { \
    LGKMN(LGN_); \
    mstep<POS>(st, (SET_).ab0, (SET_).gd0, c2p); float s0_ = st; \
    mstep<POS>(st, (SET_).ab1, (SET_).gd1, c2p); float s1_ = st; \
    mstep<POS>(st, (SET_).ab2, (SET_).gd2, c2p); float s2_ = st; \
    mstep<POS>(st, (SET_).ab3, (SET_).gd3, c2p); float s3_ = st; \
    { uint32_t wa_ = sab + (uint32_t)((Q_) * 1024); \
      asm volatile("ds_write2st64_b32 %0, %1, %2 offset0:0 offset1:1" :: "v"(wa_), "v"(s0_), "v"(s1_)); \
      asm volatile("ds_write2st64_b32 %0, %1, %2 offset0:2 offset1:3" :: "v"(wa_), "v"(s2_), "v"(s3_)); } \
    if (DORD_) { RDC(cab + (uint32_t)(((Q_) + 2) * 4096), SET_); } \
} while (0)

// producer x/r read (slot 2KB: x rows @0..768B, r rows @1024..1792B)
#define P_RD(ADDR_, B_) do { uint32_t a_ = (ADDR_); \
    asm volatile("ds_read2st64_b32 %0, %1 offset0:0 offset1:1" : "=v"((B_).x01) : "v"(a_)); \
    asm volatile("ds_read2st64_b32 %0, %1 offset0:2 offset1:3" : "=v"((B_).x23) : "v"(a_)); \
    asm volatile("ds_read2st64_b32 %0, %1 offset0:4 offset1:5" : "=v"((B_).r01) : "v"(a_)); \
    asm volatile("ds_read2st64_b32 %0, %1 offset0:6 offset1:7" : "=v"((B_).r23) : "v"(a_)); \
} while (0)

// producer step: 8 VALU + 2 coeff writes
#define PSTEP(X_, R_, O0,O1,O2,O3) do { \
    float ga_ = WF2 * (R_); \
    float de_ = fmaf(C3, (R_), 1.0f); \
    float K_  = fmaf((X_), Wi, Ck); \
    float rp_ = (R_) + 1.0f; \
    float al_ = fmaf(W12, rp_, K_ * ga_); \
    float be_ = fmaf(W13, rp_, K_ * de_); \
    asm volatile("ds_write2st64_b32 %0, %1, %2 offset0:" #O0 " offset1:" #O1 :: "v"(caddr_), "v"(al_), "v"(be_)); \
    asm volatile("ds_write2st64_b32 %0, %1, %2 offset0:" #O2 " offset1:" #O3 :: "v"(caddr_), "v"(ga_), "v"(de_)); \
} while (0)

#define P_CW(B_, CADDR_) do { uint32_t caddr_ = (CADDR_); \
    PSTEP((B_).x01.x, (B_).r01.x, 0,1,2,3); \
    PSTEP((B_).x01.y, (B_).r01.y, 4,5,6,7); \
    PSTEP((B_).x23.x, (B_).r23.x, 8,9,10,11); \
    PSTEP((B_).x23.y, (B_).r23.y, 12,13,14,15); \
} while (0)

// store duty: read st b128, hv=fma, store dwordx4 (row offset in voffset!)
#define SD_RD(ADDR_, O_) asm volatile("ds_read_b128 %0, %1" : "=v"(O_) : "v"(ADDR_))
#define SD_ST(O_, G_) do { \
    (O_).x = fmaf(WF2, (O_).x, C3); (O_).y = fmaf(WF2, (O_).y, C3); \
    (O_).z = fmaf(WF2, (O_).z, C3); (O_).w = fmaf(WF2, (O_).w, C3); \
    uint32_t vo_ = vo + (((uint32_t)(4 * (G_) + 1)) << 16); \
    asm volatile("buffer_store_dwordx4 %0, %1, %2, 0 offen" \
                 :: "v"(O_), "v"(vo_), "s"(ro)); \
} while (0)

template<bool POS>
__device__ __forceinline__ void wave0_run(
    const float* inputs, const float* returns,
    float pi_bar, float win, float wh, float bh, float wf1, float wf2,
    float* out, int b0, int lane, uint32_t crd, uint32_t swr)
{
    const int b = b0 + lane;
    const float c1 = bh - pi_bar;
    const float c2 = 2.0f * bh;
    const float c3 = pi_bar + bh;
    const float c2p = fmaxf(c2, 0.0f);

    const float h0v = inputs[b];
    out[b] = h0v;                          // row 0
    float st = (h0v - c3) / wf2;           // seed: h = wf2*st + c3 inverted

    asm volatile("" ::: "memory");
    BAR;                                   // P1
    BAR;                                   // #0: coeff batch 0 ready

    CSet SA, SB;
    for (int k = 0; k < 31; ++k) {         // batches 0..30 (8 groups)
        const uint32_t cab = crd + (uint32_t)((k & 1) * 32768);
        const uint32_t sab = swr + (uint32_t)((k & 1) * 8192);
        RDC(cab, SA); RDC(cab + 4096u, SB);
        W0_PH(0, SA, 8, 1);  W0_PH(1, SB, 10, 1);
        W0_PH(2, SA, 10, 1); W0_PH(3, SB, 10, 1);
        W0_PH(4, SA, 10, 1); W0_PH(5, SB, 10, 1);
        W0_PH(6, SA, 10, 0); W0_PH(7, SB, 2, 0);
        LGKMN(0);
        BAR;                               // #k+1
    }
    {   // batch 31: 7 groups (248..254)
        const uint32_t cab = crd + 32768u;
        const uint32_t sab = swr + 8192u;
        RDC(cab, SA); RDC(cab + 4096u, SB);
        W0_PH(0, SA, 8, 1);  W0_PH(1, SB, 10, 1);
        W0_PH(2, SA, 10, 1); W0_PH(3, SB, 10, 1);
        W0_PH(4, SA, 10, 1);
        W0_PH(5, SB, 10, 0); W0_PH(6, SA, 2, 0);
        LGKMN(0);
        BAR;                               // #32
    }
    asm volatile("" ::: "memory");

    // tail: steps 1021..1023 + hT (exact)
    float h = fmaf(wf2, st, c3);           // h_1020
#pragma unroll
    for (int s = 1021; s < S_LEN; ++s) {
        const float x = inputs[(size_t)s * B_LEN + b];
        const float r = returns[(size_t)(s - 1) * B_LEN + b];
        h = step_fn(h, x, r, win, wh, c1, c2, c3, wf1, wf2);
        out[(size_t)s * B_LEN + b] = h;
    }
    out[(size_t)S_LEN * B_LEN + b] = h;
}

__global__ __launch_bounds__(256) void wealth_rnn_kernel(
    const float* __restrict__ inputs,    // [S, B]
    const float* __restrict__ returns,   // [S-1, B]
    const float* __restrict__ target,
    const float* __restrict__ w_in_p,
    const float* __restrict__ w_h_p,
    const float* __restrict__ b_h_p,
    const float* __restrict__ w_fc1_p,
    const float* __restrict__ w_fc2_p,
    float* __restrict__ out)             // [S*B] then [B] hT
{
    __shared__ float ringf[24 * 512];     // 48 KiB x/r ring (3 batches)
    __shared__ float coefb[2 * 8192];     // 64 KiB coeff (2 banks x 8 gr x 4KB)
    __shared__ float stb[2 * 2048];       // 16 KiB st (2 banks x 8 gr x 1KB)

    const int tid  = threadIdx.x;
    const int lane = tid & 63;
    const int wid  = tid >> 6;
    const int b0   = blockIdx.x * 64;

    const float pi_bar = target[0];
    const float win = w_in_p[0];
    const float wh  = w_h_p[0];
    const float bh  = b_h_p[0];
    const float wf1 = w_fc1_p[0];
    const float wf2 = w_fc2_p[0];

    if (wid == 0) {
        const uint32_t crd = (uint32_t)(uintptr_t)&coefb[0] + (uint32_t)lane * 4u;
        const uint32_t swr = (uint32_t)(uintptr_t)&stb[0]   + (uint32_t)lane * 4u;
        if (wf1 >= 0.0f)
            wave0_run<true >(inputs, returns, pi_bar, win, wh, bh, wf1, wf2,
                             out, b0, lane, crd, swr);
        else
            wave0_run<false>(inputs, returns, pi_bar, win, wh, bh, wf1, wf2,
                             out, b0, lane, crd, swr);
    } else if (wid == 3) {
        // =========================== loader =================================
        const int j = lane;
        const int lr = j >> 4;
        const int lc = (j & 15) * 4;
        const float* gxw = inputs  + (size_t)(1 + lr) * B_LEN + b0 + lc;
        const float* grw = returns + (size_t)lr       * B_LEN + b0 + lc;
        float* ringp = &ringf[0];
        // prologue: batches 0..2 -> slots 0..23
        for (int bt = 0; bt < 3; ++bt) {
            for (int q = 0; q < 8; ++q) {
                float* lb = ringp + (size_t)(bt * 8 + q) * 512;
                dma16(gxw, lb); dma16(grw, lb + 256);
                gxw += GSTEP; grw += GSTEP;
            }
        }
        WAITV(16);                        // b0,b1 landed
        BAR;                              // P1
        WAITV(0);                         // b2 landed
        BAR;                              // #0
        for (int k = 0; k < 32; ++k) {
            if (k <= 27) {                // issue batch k+3 (8 groups)
                const int sb = (k % 3) * 8;
                for (int q = 0; q < 8; ++q) {
                    float* lb = ringp + (size_t)(sb + q) * 512;
                    dma16(gxw, lb); dma16(grw, lb + 256);
                    gxw += GSTEP; grw += GSTEP;
                }
                WAITV(16);                // thru batch k+2
            } else if (k == 28) {         // batch 31: 7 groups
                const int sb = (k % 3) * 8;
                for (int q = 0; q < 7; ++q) {
                    float* lb = ringp + (size_t)(sb + q) * 512;
                    dma16(gxw, lb); dma16(grw, lb + 256);
                    gxw += GSTEP; grw += GSTEP;
                }
                WAITV(14);                // thru batch 30
            } else if (k == 29) {
                WAITV(0);                 // all landed
            }
            BAR;                          // #k+1
        }
    } else {
        // ========================= producers (wid 1,2) ======================
        const int j = lane;
        const int goff = (wid == 1) ? 0 : 1;   // groups goff+2m
        const float C1 = bh - pi_bar;
        const float C2 = 2.0f * bh;
        const float C3 = pi_bar + bh;
        const float WF2 = wf2;
        const float Wi  = win * wf1;                 // K = x*Wi + Ck
        const float Ck  = fmaf(C1, wf1, C2);
        const float W12 = wh * wf1 * wf2;            // alpha' fold
        const float W13 = wh * wf1 * C3;             // beta' fold

        u32x4 ro = make_srsrc(out);
        const uint32_t vo = (uint32_t)((((j >> 4) * B_LEN) + b0 + (j & 15) * 4) * 4);
        const uint32_t rxr = (uint32_t)(uintptr_t)&ringf[0] + (uint32_t)lane * 4u;
        const uint32_t cwr = (uint32_t)(uintptr_t)&coefb[0] + (uint32_t)lane * 4u;
        const uint32_t stl = (uint32_t)(uintptr_t)&stb[0]
                             + (uint32_t)((j >> 4) * 256 + (j & 15) * 16);

        Bank BA, BB;
        f32x4 u0={0,0,0,0},u1={0,0,0,0},u2={0,0,0,0},u3={0,0,0,0};
        f32x4 v0={0,0,0,0},v1={0,0,0,0},v2={0,0,0,0},v3={0,0,0,0};

        asm volatile("" ::: "memory");
        BAR;                              // P1 (x/r batch 0 landed)
        {   // prologue: produce coeff batch 0 -> bank 0
            const uint32_t rb = rxr;
            const uint32_t cb = cwr;
            P_RD(rb + (uint32_t)((goff)     * 2048), BA);
            P_RD(rb + (uint32_t)((goff + 2) * 2048), BB);
            LGKMN(4);
            P_CW(BA, cb + (uint32_t)((goff)     * 4096));
            P_RD(rb + (uint32_t)((goff + 4) * 2048), BA);
            LGKMN(12);
            P_CW(BB, cb + (uint32_t)((goff + 2) * 4096));
            P_RD(rb + (uint32_t)((goff + 6) * 2048), BB);
            LGKMN(12);
            P_CW(BA, cb + (uint32_t)((goff + 4) * 4096));
            LGKMN(8);
            P_CW(BB, cb + (uint32_t)((goff + 6) * 4096));
            LGKMN(0);
        }
        BAR;                              // #0

        for (int k = 0; k < 32; ++k) {
            // ---- store duty: batch k-1 (k>=1) ----
            if (k >= 1) {
                const int bs = k - 1;
                const uint32_t sa = stl + (uint32_t)((bs & 1) * 8192);
                const int g0 = 8 * bs + goff;
                WAITV(4);                 // protect set used 2 intervals ago
                if (k & 1) {
                    asm volatile("" :: "v"(u0),"v"(u1),"v"(u2),"v"(u3));
                    SD_RD(sa + (uint32_t)((goff)     * 1024), u0);
                    SD_RD(sa + (uint32_t)((goff + 2) * 1024), u1);
                    SD_RD(sa + (uint32_t)((goff + 4) * 1024), u2);
                    if (bs < 31 || goff == 0)
                        SD_RD(sa + (uint32_t)((goff + 6) * 1024), u3);
                    LGKMN(0);
                    SD_ST(u0, g0); SD_ST(u1, g0 + 2); SD_ST(u2, g0 + 4);
                    if (bs < 31 || goff == 0) SD_ST(u3, g0 + 6);
                } else {
                    asm volatile("" :: "v"(v0),"v"(v1),"v"(v2),"v"(v3));
                    SD_RD(sa + (uint32_t)((goff)     * 1024), v0);
                    SD_RD(sa + (uint32_t)((goff + 2) * 1024), v1);
                    SD_RD(sa + (uint32_t)((goff + 4) * 1024), v2);
                    if (bs < 31 || goff == 0)
                        SD_RD(sa + (uint32_t)((goff + 6) * 1024), v3);
                    LGKMN(0);
                    SD_ST(v0, g0); SD_ST(v1, g0 + 2); SD_ST(v2, g0 + 4);
                    if (bs < 31 || goff == 0) SD_ST(v3, g0 + 6);
                }
            }
            // ---- production: batch k+1 (k<=30) ----
            if (k <= 30) {
                const int bp = k + 1;
                const uint32_t rb = rxr + (uint32_t)(((bp % 3) * 8) * 2048);
                const uint32_t cb = cwr + (uint32_t)((bp & 1) * 32768);
                const bool full = (bp < 31) || (goff == 0);  // 4 vs 3 groups
                P_RD(rb + (uint32_t)((goff)     * 2048), BA);
                P_RD(rb + (uint32_t)((goff + 2) * 2048), BB);
                LGKMN(4);
                P_CW(BA, cb + (uint32_t)((goff)     * 4096));
                P_RD(rb + (uint32_t)((goff + 4) * 2048), BA);
                LGKMN(12);
                P_CW(BB, cb + (uint32_t)((goff + 2) * 4096));
                if (full) {
                    P_RD(rb + (uint32_t)((goff + 6) * 2048), BB);
                    LGKMN(12);
                    P_CW(BA, cb + (uint32_t)((goff + 4) * 4096));
                    LGKMN(8);
                    P_CW(BB, cb + (uint32_t)((goff + 6) * 4096));
                } else {
                    LGKMN(8);
                    P_CW(BA, cb + (uint32_t)((goff + 4) * 4096));
                }
                LGKMN(0);
            }
            BAR;                          // #k+1
        }
        // ---- final stores: batch 31 (after bar #32) ----
        {
            const int bs = 31;
            const uint32_t sa = stl + (uint32_t)((bs & 1) * 8192);
            const int g0 = 8 * bs + goff;
            WAITV(4);
            asm volatile("" :: "v"(u0),"v"(u1),"v"(u2),"v"(u3));
            SD_RD(sa + (uint32_t)((goff)     * 1024), u0);
            SD_RD(sa + (uint32_t)((goff + 2) * 1024), u1);
            SD_RD(sa + (uint32_t)((goff + 4) * 1024), u2);
            if (goff == 0) SD_RD(sa + (uint32_t)((goff + 6) * 1024), u3);
            LGKMN(0);
            SD_ST(u0, g0); SD_ST(u1, g0 + 2); SD_ST(u2, g0 + 4);
            if (goff == 0) SD_ST(u3, g0 + 6);
            WAITV(0);
        }
    }
}

extern "C" void kernel_launch(void* const* d_in, const int* in_sizes, int n_in,
                              void* d_out, int out_size, void* d_ws, size_t ws_size,
                              hipStream_t stream) {
    const float* inputs  = (const float*)d_in[0];
    const float* returns = (const float*)d_in[1];
    const float* target  = (const float*)d_in[2];
    const float* w_in    = (const float*)d_in[3];
    const float* w_h     = (const float*)d_in[4];
    const float* b_h     = (const float*)d_in[5];
    const float* w_fc1   = (const float*)d_in[6];
    const float* w_fc2   = (const float*)d_in[7];
    float* out = (float*)d_out;

    dim3 grid(B_LEN / 64);
    dim3 block(256);
    hipLaunchKernelGGL(wealth_rnn_kernel, grid, block, 0, stream,
                       inputs, returns, target, w_in, w_h, b_h, w_fc1, w_fc2, out);
}